// Round 2
// baseline (157.902 us; speedup 1.0000x reference)
//
#include <hip/hip_runtime.h>

#define B 4
#define N 512
#define M 8192
#define H 8
#define DH 16
#define DIM 128
#define J (M + N)          // 8704
#define LN10000_DIV8 1.1512925465f   // ln(10000)/8
#define LOG2E 1.44269504f

typedef _Float16 f16;
typedef _Float16 half4 __attribute__((ext_vector_type(4)));
typedef _Float16 half8 __attribute__((ext_vector_type(8)));
typedef __fp16 fp16x2 __attribute__((ext_vector_type(2)));
typedef float f32x4 __attribute__((ext_vector_type(4)));

#if __has_builtin(__builtin_amdgcn_exp2f)
#define EXP2(x) __builtin_amdgcn_exp2f(x)
#else
#define EXP2(x) exp2f(x)
#endif

union PK { fp16x2 v; unsigned int u; };

__device__ __forceinline__ half8 pack8(float a, float b, float c, float d,
                                       float e, float f, float g, float h) {
#if __has_builtin(__builtin_amdgcn_cvt_pkrtz)
    union { unsigned int u[4]; half8 h8; } r;
    PK p0, p1, p2, p3;
    p0.v = __builtin_amdgcn_cvt_pkrtz(a, b);
    p1.v = __builtin_amdgcn_cvt_pkrtz(c, d);
    p2.v = __builtin_amdgcn_cvt_pkrtz(e, f);
    p3.v = __builtin_amdgcn_cvt_pkrtz(g, h);
    r.u[0] = p0.u; r.u[1] = p1.u; r.u[2] = p2.u; r.u[3] = p3.u;
    return r.h8;
#else
    half8 r = { (f16)a, (f16)b, (f16)c, (f16)d, (f16)e, (f16)f, (f16)g, (f16)h };
    return r;
#endif
}

// ---- workspace layout ----
#define WS_KROT 0ull                              // f16 [32][J/32][512]  8,912,896 B (MFMA-frag tile order)
#define WS_VT   8912896ull                        // f16 [32][16][J]      8,912,896 B
#define WS_QROT 17825792ull                       // f16 [32][512][16]      524,288 B
#define WS_HV   18350080ull                       // f16 [2048][128]        524,288 B
#define WS_XN   18874368ull                       // f16 [2048][128]        524,288 B (dies after proj)

union K16 { f16 h[16]; uint4 u[2]; };
union V4  { f16 h[4];  uint2 u; };

__device__ __forceinline__ half8 cvt8(const float* p) {
    float4 a = *(const float4*)p, b = *(const float4*)(p + 4);
    half8 h = { (f16)a.x, (f16)a.y, (f16)a.z, (f16)a.w,
                (f16)b.x, (f16)b.y, (f16)b.z, (f16)b.w };
    return h;
}

// ---------------------------------------------------------------------------
// Kernel 1: prep. Blocks 0..4095: read old mem_kv, emit repacked rotated-K +
// V^T (fp32 copy-out moved into attn_kernel filler blocks — it feeds nothing
// downstream, so it no longer serializes in front of proj/attn).
// Blocks 4096..4607: LN1 -> xn16 (f16).
// ---------------------------------------------------------------------------
__global__ void prep_kernel(const float4* __restrict__ src,
                            f16* __restrict__ krot, f16* __restrict__ vt,
                            const float* __restrict__ x, const float* __restrict__ g1,
                            const float* __restrict__ b1, f16* __restrict__ xn16)
{
    if (blockIdx.x < 4096) {
        __shared__ float tile[64][33];
        int bh = blockIdx.x >> 7;
        int j0 = (blockIdx.x & 127) * 64;
        int t = threadIdx.x;

        #pragma unroll
        for (int rep = 0; rep < 2; rep++) {
            int idx = t + rep * 256;
            int row = idx >> 3, c4 = idx & 7;
            float4 v = src[((size_t)bh * M + j0 + row) * 8 + c4];
            tile[row][c4 * 4 + 0] = v.x; tile[row][c4 * 4 + 1] = v.y;
            tile[row][c4 * 4 + 2] = v.z; tile[row][c4 * 4 + 3] = v.w;
        }
        __syncthreads();

        if (t < 128) {                      // rotated K: 2 threads/row, 4 sincos each
            int row = t >> 1, rh = t & 1;
            int j = j0 + row;
            float lo4[4], hi4[4];
            #pragma unroll
            for (int i = 0; i < 4; i++) {
                int r = rh * 4 + i;
                float ang = (float)j * __expf(-(float)r * LN10000_DIV8);
                float sn, cs; __sincosf(ang, &sn, &cs);
                float lo = tile[row][r], hi = tile[row][r + 8];
                lo4[i] = lo * cs - hi * sn;
                hi4[i] = hi * cs + lo * sn;
            }
            int tilei = j >> 5, jj = j & 31;
            int col4 = (jj >> 3) * 4 + (jj & 3), frag = (jj >> 2) & 1;
            f16* base = krot + (size_t)bh * J * 16 + (size_t)tilei * 512 + col4 * 8 + frag * 4;
            V4 wl, wh;
            #pragma unroll
            for (int i = 0; i < 4; i++) { wl.h[i] = (f16)lo4[i]; wh.h[i] = (f16)hi4[i]; }
            *(uint2*)(base + rh * 128)       = wl.u;   // dims rh*4 .. rh*4+3
            *(uint2*)(base + (2 + rh) * 128) = wh.u;   // dims 8+rh*4 .. 8+rh*4+3
        }
        {                                   // V^T: dh-major, j contiguous
            int dh = t >> 4, c0 = (t & 15) * 4;
            V4 vv;
            #pragma unroll
            for (int i = 0; i < 4; i++) vv.h[i] = (f16)tile[c0 + i][16 + dh];
            *(uint2*)(vt + (size_t)bh * 16 * J + (size_t)dh * J + j0 + c0) = vv.u;
        }
    } else {
        int wave = threadIdx.x >> 6, lane = threadIdx.x & 63;
        int token = (blockIdx.x - 4096) * 4 + wave;
        float v0 = x[(size_t)token * DIM + lane];
        float v1 = x[(size_t)token * DIM + lane + 64];
        float s = v0 + v1;
        for (int off = 32; off; off >>= 1) s += __shfl_xor(s, off, 64);
        float mu = s * (1.0f / DIM);
        float d0 = v0 - mu, d1 = v1 - mu;
        float vs = d0 * d0 + d1 * d1;
        for (int off = 32; off; off >>= 1) vs += __shfl_xor(vs, off, 64);
        float rs = rsqrtf(vs * (1.0f / DIM) + 1e-5f);
        xn16[(size_t)token * DIM + lane]      = (f16)(d0 * rs * g1[lane]      + b1[lane]);
        xn16[(size_t)token * DIM + lane + 64] = (f16)(d1 * rs * g1[lane + 64] + b1[lane + 64]);
    }
}

// ---------------------------------------------------------------------------
// Kernel 2: MFMA projection GEMM: [2048 tok x 128] @ [384 cols x 128]^T.
// Weights converted fp32->fp16 inline. One 16x16 tile per wave; 768 blocks.
// ctile 0..7: Q head=ctile. ctile 8..23: kv-tile kt: head=kt>>1, V iff kt&1.
// Q output folds 0.25 * log2(e) so attn can use exp2.
// ---------------------------------------------------------------------------
__global__ void __launch_bounds__(256) proj_kernel(
    const f16* __restrict__ xn16, const float* __restrict__ wq,
    const float* __restrict__ wkv, float* __restrict__ out_mem,
    f16* __restrict__ krot, f16* __restrict__ vt, f16* __restrict__ qrot)
{
    int id = blockIdx.x * 4 + (threadIdx.x >> 6);
    int lane = threadIdx.x & 63;
    int ttile = id & 127, ctile = id >> 7;
    int token0 = ttile * 16;
    int col = lane & 15, quad = lane >> 4;

    const float* wbase = (ctile < 8) ? (wq + (size_t)(ctile * 16 + col) * DIM)
                                     : (wkv + (size_t)((ctile - 8) * 16 + col) * DIM);
    const f16* abase = xn16 + (size_t)(token0 + col) * DIM + quad * 8;

    f32x4 acc = {0.f, 0.f, 0.f, 0.f};
    #pragma unroll
    for (int kb = 0; kb < 4; kb++) {
        half8 a = *(const half8*)(abase + kb * 32);
        half8 w = cvt8(wbase + kb * 32 + quad * 8);
        acc = __builtin_amdgcn_mfma_f32_16x16x32_f16(a, w, acc, 0, 0, 0);
    }

    int e = col, r8 = e & 7;
    float f = __expf(-(float)r8 * LN10000_DIV8);
    int kt = ctile - 8;
    int head = (ctile < 8) ? ctile : (kt >> 1);
    int isV  = (ctile >= 8) ? (kt & 1) : 0;

    #pragma unroll
    for (int r = 0; r < 4; r++) {
        int tok = token0 + quad * 4 + r;
        int b = tok >> 9, i = tok & (N - 1);
        int bhh = b * H + head;
        float self = acc[r];
        float prt = __shfl_xor(self, 8, 64);      // partner dim e^8, same token

        if (ctile < 8) {                          // Q: rotary + scale (incl. log2e)
            float ang = (float)(M + i) * f;
            float sn, cs; __sincosf(ang, &sn, &cs);
            float rv = (self * cs + ((e < 8) ? -prt : prt) * sn) * (0.25f * LOG2E);
            qrot[((size_t)bhh * N + i) * 16 + e] = (f16)rv;
        } else if (!isV) {                        // K: fp32 append + repacked rotated fp16
            out_mem[((size_t)bhh * J + M + i) * 32 + e] = self;
            float ang = (float)(M + i) * f;
            float sn, cs; __sincosf(ang, &sn, &cs);
            float rv = self * cs + ((e < 8) ? -prt : prt) * sn;
            int jpos = M + i;
            int tilei = jpos >> 5, jj = jpos & 31;
            int col4 = (jj >> 3) * 4 + (jj & 3), frag = (jj >> 2) & 1;
            krot[(size_t)bhh * J * 16 + (size_t)tilei * 512 +
                 (e >> 2) * 128 + col4 * 8 + frag * 4 + (e & 3)] = (f16)rv;
        } else {                                  // V: fp32 append + fp16 V^T
            out_mem[((size_t)bhh * J + M + i) * 32 + 16 + e] = self;
            vt[(size_t)bhh * 16 * J + (size_t)e * J + M + i] = (f16)self;
        }
    }
}

// ---------------------------------------------------------------------------
// Kernel 3: MFMA flash attention + fused mem_kv fp32 copy-out.
// Grid = 2560 blocks: every 5th block (blockIdx%5==0) is a compute block
// (cid = blockIdx/5, 0..511: 32 bh * 16 qgroups); the other 2048 are copy
// filler blocks streaming old mem_kv -> out_mem with nontemporal ld/st
// (no L2 pollution of the XCD-resident krot/vt the compute blocks reuse).
// bh -> XCD mapping preserved: physical id 5*cid, 5*(bh+32k) mod 8 = 5bh mod 8.
// Compute: per wave 2 q-tiles, J/8 keys; no-max softmax via raw exp2.
// ---------------------------------------------------------------------------
__global__ void __launch_bounds__(512, 4) attn_kernel(
    const f16* __restrict__ krot, const f16* __restrict__ vt,
    const f16* __restrict__ qrot, f16* __restrict__ hvw,
    const f32x4* __restrict__ csrc, f32x4* __restrict__ cdst)
{
    __shared__ float sacc[8][2][256];
    __shared__ float sl[8][2][16];

    if (blockIdx.x % 5 != 0) {              // ---- copy filler block ----
        int t = threadIdx.x;
        size_t copyid = (size_t)blockIdx.x - blockIdx.x / 5 - 1;   // 0..2047
        size_t base = copyid * 1024;
        #pragma unroll
        for (int rep = 0; rep < 2; rep++) {
            size_t flat = base + rep * 512 + t;         // over [bh][M][8 f4]
            int bh  = (int)(flat >> 16);                // M*8 = 65536
            int rem = (int)(flat & 65535);              // = j*8 + c4
            f32x4 v = __builtin_nontemporal_load(csrc + flat);
            __builtin_nontemporal_store(v, cdst + (size_t)bh * (J * 8) + rem);
        }
        return;
    }

    int cid = blockIdx.x / 5;               // 0..511
    int bh = cid & 31;                      // same-bh blocks -> same XCD
    int q0 = (cid >> 5) * 32;
    int wave = threadIdx.x >> 6, lane = threadIdx.x & 63;
    int col = lane & 15, quad = lane >> 4;

    const f16* vb = vt + (size_t)bh * 16 * J + (size_t)col * J;
    half4 qfa = *(const half4*)(qrot + ((size_t)bh * N + q0 + col) * 16 + quad * 4);
    half4 qfb = *(const half4*)(qrot + ((size_t)bh * N + q0 + 16 + col) * 16 + quad * 4);

    int jstart = wave * (J / 8);            // 1088 = 34 iters of 32 keys
    const f16* kptr = krot + (size_t)bh * J * 16 + (size_t)jstart * 16 + lane * 8;
    const f16* vptr = vb + jstart + quad * 8;

    f32x4 acca = {0.f, 0.f, 0.f, 0.f};
    f32x4 accb = {0.f, 0.f, 0.f, 0.f};
    const f32x4 zero = {0.f, 0.f, 0.f, 0.f};
    float la = 0.f, lb = 0.f;

    #pragma unroll 2
    for (int it = 0; it < 34; ++it) {
        half8 kf8 = *(const half8*)kptr;
        half8 vf  = *(const half8*)vptr;
        kptr += 512; vptr += 32;
        half4 kf0 = __builtin_shufflevector(kf8, kf8, 0, 1, 2, 3);
        half4 kf1 = __builtin_shufflevector(kf8, kf8, 4, 5, 6, 7);
        __builtin_amdgcn_s_setprio(1);
        f32x4 s0a = __builtin_amdgcn_mfma_f32_16x16x16f16(kf0, qfa, zero, 0, 0, 0);
        f32x4 s1a = __builtin_amdgcn_mfma_f32_16x16x16f16(kf1, qfa, zero, 0, 0, 0);
        f32x4 s0b = __builtin_amdgcn_mfma_f32_16x16x16f16(kf0, qfb, zero, 0, 0, 0);
        f32x4 s1b = __builtin_amdgcn_mfma_f32_16x16x16f16(kf1, qfb, zero, 0, 0, 0);
        __builtin_amdgcn_s_setprio(0);

        float a0 = EXP2(s0a[0]), a1 = EXP2(s0a[1]), a2 = EXP2(s0a[2]), a3 = EXP2(s0a[3]);
        float a4 = EXP2(s1a[0]), a5 = EXP2(s1a[1]), a6 = EXP2(s1a[2]), a7 = EXP2(s1a[3]);
        float b0 = EXP2(s0b[0]), b1 = EXP2(s0b[1]), b2 = EXP2(s0b[2]), b3 = EXP2(s0b[3]);
        float b4 = EXP2(s1b[0]), b5 = EXP2(s1b[1]), b6 = EXP2(s1b[2]), b7 = EXP2(s1b[3]);
        la += ((a0 + a1) + (a2 + a3)) + ((a4 + a5) + (a6 + a7));
        lb += ((b0 + b1) + (b2 + b3)) + ((b4 + b5) + (b6 + b7));
        half8 pfa = pack8(a0, a1, a2, a3, a4, a5, a6, a7);
        half8 pfb = pack8(b0, b1, b2, b3, b4, b5, b6, b7);
        __builtin_amdgcn_s_setprio(1);
        acca = __builtin_amdgcn_mfma_f32_16x16x32_f16(pfa, vf, acca, 0, 0, 0);
        accb = __builtin_amdgcn_mfma_f32_16x16x32_f16(pfb, vf, accb, 0, 0, 0);
        __builtin_amdgcn_s_setprio(0);
    }

    la += __shfl_xor(la, 16, 64);
    la += __shfl_xor(la, 32, 64);
    lb += __shfl_xor(lb, 16, 64);
    lb += __shfl_xor(lb, 32, 64);
    if (quad == 0) { sl[wave][0][col] = la; sl[wave][1][col] = lb; }
    #pragma unroll
    for (int r = 0; r < 4; r++) {
        sacc[wave][0][(quad * 4 + r) * 16 + col] = acca[r];
        sacc[wave][1][(quad * 4 + r) * 16 + col] = accb[r];
    }
    __syncthreads();

    if (wave < 2) {                         // wave 0 -> q-tile 0, wave 1 -> q-tile 1
        int qt = wave;
        int b = bh >> 3, h = bh & 7;
        #pragma unroll
        for (int r = 0; r < 4; r++) {
            int ql = quad * 4 + r;
            float o = 0.f, lt = 0.f;
            #pragma unroll
            for (int w = 0; w < 8; w++) {
                o  += sacc[w][qt][ql * 16 + col];
                lt += sl[w][qt][ql];
            }
            hvw[((size_t)(b * N) + q0 + qt * 16 + ql) * DIM + h * DH + col] = (f16)(o / lt);
        }
    }
}

// ---------------------------------------------------------------------------
// Kernel 4: fused residual + LN2 + MFMA out-proj + residual.
// grid = 256 blocks (16 tokens, 4 of 8 col-tiles each; LN duplicated x2),
// 256 thr = 4 waves. Doubles CU coverage vs the 128-block version.
// ---------------------------------------------------------------------------
__global__ void __launch_bounds__(256) final_kernel(
    const f16* __restrict__ hvw, const float* __restrict__ x,
    const float* __restrict__ wout, const float* __restrict__ bout,
    const float* __restrict__ g2, const float* __restrict__ b2v,
    float* __restrict__ out)
{
    __shared__ f16 xn2[16][136];
    __shared__ float hres[16][132];
    int token0 = (blockIdx.x >> 1) * 16;
    int half = blockIdx.x & 1;
    int wave = threadIdx.x >> 6, lane = threadIdx.x & 63;

    #pragma unroll
    for (int tt = 0; tt < 4; tt++) {
        int tl = wave * 4 + tt;
        int token = token0 + tl;
        float h0 = (float)hvw[(size_t)token * DIM + lane]      + x[(size_t)token * DIM + lane];
        float h1 = (float)hvw[(size_t)token * DIM + lane + 64] + x[(size_t)token * DIM + lane + 64];
        float s = h0 + h1;
        for (int off = 32; off; off >>= 1) s += __shfl_xor(s, off, 64);
        float mu = s * (1.0f / DIM);
        float d0 = h0 - mu, d1 = h1 - mu;
        float vs = d0 * d0 + d1 * d1;
        for (int off = 32; off; off >>= 1) vs += __shfl_xor(vs, off, 64);
        float rs = rsqrtf(vs * (1.0f / DIM) + 1e-5f);
        xn2[tl][lane]      = (f16)(d0 * rs * g2[lane]      + b2v[lane]);
        xn2[tl][lane + 64] = (f16)(d1 * rs * g2[lane + 64] + b2v[lane + 64]);
        hres[tl][lane] = h0; hres[tl][lane + 64] = h1;
    }
    __syncthreads();

    int col = lane & 15, quad = lane >> 4;
    int ct = half * 4 + wave;               // this block's 4 col-tiles
    int cg = ct * 16 + col;
    const float* wrow = wout + (size_t)cg * DIM;
    f32x4 acc = {0.f, 0.f, 0.f, 0.f};
    #pragma unroll
    for (int kb = 0; kb < 4; kb++) {
        half8 a = *(const half8*)(&xn2[col][kb * 32 + quad * 8]);
        half8 w = cvt8(wrow + kb * 32 + quad * 8);
        acc = __builtin_amdgcn_mfma_f32_16x16x32_f16(a, w, acc, 0, 0, 0);
    }
    float bo = bout[cg];
    #pragma unroll
    for (int r = 0; r < 4; r++) {
        int tl = quad * 4 + r;
        out[(size_t)(token0 + tl) * DIM + cg] = acc[r] + bo + hres[tl][cg];
    }
}

// ===========================================================================
extern "C" void kernel_launch(void* const* d_in, const int* in_sizes, int n_in,
                              void* d_out, int out_size, void* d_ws, size_t ws_size,
                              hipStream_t stream)
{
    const float* x      = (const float*)d_in[0];
    const float* mem_kv = (const float*)d_in[1];
    const float* wq     = (const float*)d_in[2];
    const float* wkv    = (const float*)d_in[3];
    const float* wout   = (const float*)d_in[4];
    const float* bout   = (const float*)d_in[5];
    const float* g1     = (const float*)d_in[6];
    const float* b1     = (const float*)d_in[7];
    const float* g2     = (const float*)d_in[8];
    const float* b2     = (const float*)d_in[9];

    float* out = (float*)d_out;
    float* out_mem = out + (size_t)B * N * DIM;

    f16* krot = (f16*)((char*)d_ws + WS_KROT);
    f16* vt   = (f16*)((char*)d_ws + WS_VT);
    f16* qrot = (f16*)((char*)d_ws + WS_QROT);
    f16* hvw  = (f16*)((char*)d_ws + WS_HV);
    f16* xn16 = (f16*)((char*)d_ws + WS_XN);

    hipLaunchKernelGGL(prep_kernel, dim3(4608), dim3(256), 0, stream,
                       (const float4*)mem_kv, krot, vt, x, g1, b1, xn16);
    hipLaunchKernelGGL(proj_kernel, dim3(768), dim3(256), 0, stream,
                       xn16, wq, wkv, out_mem, krot, vt, qrot);
    hipLaunchKernelGGL(attn_kernel, dim3(2560), dim3(512), 0, stream,
                       krot, vt, qrot, hvw,
                       (const f32x4*)mem_kv, (f32x4*)out_mem);
    hipLaunchKernelGGL(final_kernel, dim3(256), dim3(256), 0, stream,
                       hvw, x, wout, bout, g2, b2, out);
}

// Round 3
// 141.633 us; speedup vs baseline: 1.1149x; 1.1149x over previous
//
#include <hip/hip_runtime.h>

#define B 4
#define N 512
#define M 8192
#define H 8
#define DH 16
#define DIM 128
#define J (M + N)          // 8704
#define LN10000_DIV8 1.1512925465f   // ln(10000)/8
#define LOG2E 1.44269504f

typedef _Float16 f16;
typedef _Float16 half4 __attribute__((ext_vector_type(4)));
typedef _Float16 half8 __attribute__((ext_vector_type(8)));
typedef __fp16 fp16x2 __attribute__((ext_vector_type(2)));
typedef float f32x4 __attribute__((ext_vector_type(4)));

#if __has_builtin(__builtin_amdgcn_exp2f)
#define EXP2(x) __builtin_amdgcn_exp2f(x)
#else
#define EXP2(x) exp2f(x)
#endif

union PK { fp16x2 v; unsigned int u; };

__device__ __forceinline__ half8 pack8(float a, float b, float c, float d,
                                       float e, float f, float g, float h) {
#if __has_builtin(__builtin_amdgcn_cvt_pkrtz)
    union { unsigned int u[4]; half8 h8; } r;
    PK p0, p1, p2, p3;
    p0.v = __builtin_amdgcn_cvt_pkrtz(a, b);
    p1.v = __builtin_amdgcn_cvt_pkrtz(c, d);
    p2.v = __builtin_amdgcn_cvt_pkrtz(e, f);
    p3.v = __builtin_amdgcn_cvt_pkrtz(g, h);
    r.u[0] = p0.u; r.u[1] = p1.u; r.u[2] = p2.u; r.u[3] = p3.u;
    return r.h8;
#else
    half8 r = { (f16)a, (f16)b, (f16)c, (f16)d, (f16)e, (f16)f, (f16)g, (f16)h };
    return r;
#endif
}

// ---- workspace layout ----
#define WS_KROT 0ull                              // f16 [32][J/32][512]  8,912,896 B (MFMA-frag tile order)
#define WS_VT   8912896ull                        // f16 [32][16][J]      8,912,896 B
#define WS_QROT 17825792ull                       // f16 [32][512][16]      524,288 B
#define WS_HV   18350080ull                       // f16 [2048][128]        524,288 B
#define WS_XN   18874368ull                       // f16 [2048][128]        524,288 B (dies after proj)

union V4  { f16 h[4];  uint2 u; };

__device__ __forceinline__ half8 cvt8(const float* p) {
    float4 a = *(const float4*)p, b = *(const float4*)(p + 4);
    half8 h = { (f16)a.x, (f16)a.y, (f16)a.z, (f16)a.w,
                (f16)b.x, (f16)b.y, (f16)b.z, (f16)b.w };
    return h;
}

// ---------------------------------------------------------------------------
// Kernel 1: merged prep. Blocks 0..4095: copy old mem_kv (fp32, rides the
// already-BW-bound kernel) + emit repacked rotated-K + V^T.
// Blocks 4096..4607: LN1 -> xn16 (f16).
// ---------------------------------------------------------------------------
__global__ void prep_kernel(const float4* __restrict__ src, float4* __restrict__ dst,
                            f16* __restrict__ krot, f16* __restrict__ vt,
                            const float* __restrict__ x, const float* __restrict__ g1,
                            const float* __restrict__ b1, f16* __restrict__ xn16)
{
    if (blockIdx.x < 4096) {
        __shared__ float tile[64][33];
        int bh = blockIdx.x >> 7;
        int j0 = (blockIdx.x & 127) * 64;
        int t = threadIdx.x;

        #pragma unroll
        for (int rep = 0; rep < 2; rep++) {
            int idx = t + rep * 256;
            int row = idx >> 3, c4 = idx & 7;
            float4 v = src[((size_t)bh * M + j0 + row) * 8 + c4];
            dst[((size_t)bh * J + j0 + row) * 8 + c4] = v;
            tile[row][c4 * 4 + 0] = v.x; tile[row][c4 * 4 + 1] = v.y;
            tile[row][c4 * 4 + 2] = v.z; tile[row][c4 * 4 + 3] = v.w;
        }
        __syncthreads();

        if (t < 128) {                      // rotated K: 2 threads/row, 4 sincos each
            int row = t >> 1, rh = t & 1;
            int j = j0 + row;
            float lo4[4], hi4[4];
            #pragma unroll
            for (int i = 0; i < 4; i++) {
                int r = rh * 4 + i;
                float ang = (float)j * __expf(-(float)r * LN10000_DIV8);
                float sn, cs; __sincosf(ang, &sn, &cs);
                float lo = tile[row][r], hi = tile[row][r + 8];
                lo4[i] = lo * cs - hi * sn;
                hi4[i] = hi * cs + lo * sn;
            }
            int tilei = j >> 5, jj = j & 31;
            int col4 = (jj >> 3) * 4 + (jj & 3), frag = (jj >> 2) & 1;
            f16* base = krot + (size_t)bh * J * 16 + (size_t)tilei * 512 + col4 * 8 + frag * 4;
            V4 wl, wh;
            #pragma unroll
            for (int i = 0; i < 4; i++) { wl.h[i] = (f16)lo4[i]; wh.h[i] = (f16)hi4[i]; }
            *(uint2*)(base + rh * 128)       = wl.u;   // dims rh*4 .. rh*4+3
            *(uint2*)(base + (2 + rh) * 128) = wh.u;   // dims 8+rh*4 .. 8+rh*4+3
        }
        {                                   // V^T: dh-major, j contiguous
            int dh = t >> 4, c0 = (t & 15) * 4;
            V4 vv;
            #pragma unroll
            for (int i = 0; i < 4; i++) vv.h[i] = (f16)tile[c0 + i][16 + dh];
            *(uint2*)(vt + (size_t)bh * 16 * J + (size_t)dh * J + j0 + c0) = vv.u;
        }
    } else {
        int wave = threadIdx.x >> 6, lane = threadIdx.x & 63;
        int token = (blockIdx.x - 4096) * 4 + wave;
        float v0 = x[(size_t)token * DIM + lane];
        float v1 = x[(size_t)token * DIM + lane + 64];
        float s = v0 + v1;
        for (int off = 32; off; off >>= 1) s += __shfl_xor(s, off, 64);
        float mu = s * (1.0f / DIM);
        float d0 = v0 - mu, d1 = v1 - mu;
        float vs = d0 * d0 + d1 * d1;
        for (int off = 32; off; off >>= 1) vs += __shfl_xor(vs, off, 64);
        float rs = rsqrtf(vs * (1.0f / DIM) + 1e-5f);
        xn16[(size_t)token * DIM + lane]      = (f16)(d0 * rs * g1[lane]      + b1[lane]);
        xn16[(size_t)token * DIM + lane + 64] = (f16)(d1 * rs * g1[lane + 64] + b1[lane + 64]);
    }
}

// ---------------------------------------------------------------------------
// Kernel 2: MFMA projection GEMM: [2048 tok x 128] @ [384 cols x 128]^T.
// Weights converted fp32->fp16 inline. One 16x16 tile per wave; 768 blocks.
// ctile 0..7: Q head=ctile. ctile 8..23: kv-tile kt: head=kt>>1, V iff kt&1.
// Q output folds 0.25 * log2(e) so attn can use exp2.
// ---------------------------------------------------------------------------
__global__ void __launch_bounds__(256) proj_kernel(
    const f16* __restrict__ xn16, const float* __restrict__ wq,
    const float* __restrict__ wkv, float* __restrict__ out_mem,
    f16* __restrict__ krot, f16* __restrict__ vt, f16* __restrict__ qrot)
{
    int id = blockIdx.x * 4 + (threadIdx.x >> 6);
    int lane = threadIdx.x & 63;
    int ttile = id & 127, ctile = id >> 7;
    int token0 = ttile * 16;
    int col = lane & 15, quad = lane >> 4;

    const float* wbase = (ctile < 8) ? (wq + (size_t)(ctile * 16 + col) * DIM)
                                     : (wkv + (size_t)((ctile - 8) * 16 + col) * DIM);
    const f16* abase = xn16 + (size_t)(token0 + col) * DIM + quad * 8;

    f32x4 acc = {0.f, 0.f, 0.f, 0.f};
    #pragma unroll
    for (int kb = 0; kb < 4; kb++) {
        half8 a = *(const half8*)(abase + kb * 32);
        half8 w = cvt8(wbase + kb * 32 + quad * 8);
        acc = __builtin_amdgcn_mfma_f32_16x16x32_f16(a, w, acc, 0, 0, 0);
    }

    int e = col, r8 = e & 7;
    float f = __expf(-(float)r8 * LN10000_DIV8);
    int kt = ctile - 8;
    int head = (ctile < 8) ? ctile : (kt >> 1);
    int isV  = (ctile >= 8) ? (kt & 1) : 0;

    #pragma unroll
    for (int r = 0; r < 4; r++) {
        int tok = token0 + quad * 4 + r;
        int b = tok >> 9, i = tok & (N - 1);
        int bhh = b * H + head;
        float self = acc[r];
        float prt = __shfl_xor(self, 8, 64);      // partner dim e^8, same token

        if (ctile < 8) {                          // Q: rotary + scale (incl. log2e)
            float ang = (float)(M + i) * f;
            float sn, cs; __sincosf(ang, &sn, &cs);
            float rv = (self * cs + ((e < 8) ? -prt : prt) * sn) * (0.25f * LOG2E);
            qrot[((size_t)bhh * N + i) * 16 + e] = (f16)rv;
        } else if (!isV) {                        // K: fp32 append + repacked rotated fp16
            out_mem[((size_t)bhh * J + M + i) * 32 + e] = self;
            float ang = (float)(M + i) * f;
            float sn, cs; __sincosf(ang, &sn, &cs);
            float rv = self * cs + ((e < 8) ? -prt : prt) * sn;
            int jpos = M + i;
            int tilei = jpos >> 5, jj = jpos & 31;
            int col4 = (jj >> 3) * 4 + (jj & 3), frag = (jj >> 2) & 1;
            krot[(size_t)bhh * J * 16 + (size_t)tilei * 512 +
                 (e >> 2) * 128 + col4 * 8 + frag * 4 + (e & 3)] = (f16)rv;
        } else {                                  // V: fp32 append + fp16 V^T
            out_mem[((size_t)bhh * J + M + i) * 32 + 16 + e] = self;
            vt[(size_t)bhh * 16 * J + (size_t)e * J + M + i] = (f16)self;
        }
    }
}

// ---------------------------------------------------------------------------
// Kernel 3: MFMA flash attention, no-max softmax via raw exp2.
// grid = 512 blocks (32 bh low-bits -> XCD-local L2 reuse, 16 qgroups of 32q)
// x 1024 threads = 16 waves -> 32 waves/CU (100% occupancy ceiling; was 50%).
// Each wave: 2 q-tiles, J/16 = 544 keys (17 iters). Softmax denominator
// accumulated on the (idle) MFMA pipe via all-ones B operand.
// ---------------------------------------------------------------------------
__global__ void __launch_bounds__(1024) attn_kernel(
    const f16* __restrict__ krot, const f16* __restrict__ vt,
    const f16* __restrict__ qrot, f16* __restrict__ hvw)
{
    __shared__ float sacc[16][2][256];
    __shared__ float sl[16][2][16];
    int bh = blockIdx.x & 31;               // same-bh blocks -> same XCD
    int q0 = (blockIdx.x >> 5) * 32;
    int wave = threadIdx.x >> 6, lane = threadIdx.x & 63;
    int col = lane & 15, quad = lane >> 4;

    const f16* vb = vt + (size_t)bh * 16 * J + (size_t)col * J;
    half4 qfa = *(const half4*)(qrot + ((size_t)bh * N + q0 + col) * 16 + quad * 4);
    half4 qfb = *(const half4*)(qrot + ((size_t)bh * N + q0 + 16 + col) * 16 + quad * 4);

    int jstart = wave * (J / 16);           // 544 = 17 iters of 32 keys
    const f16* kptr = krot + (size_t)bh * J * 16 + (size_t)jstart * 16 + lane * 8;
    const f16* vptr = vb + jstart + quad * 8;

    f32x4 acca = {0.f, 0.f, 0.f, 0.f};
    f32x4 accb = {0.f, 0.f, 0.f, 0.f};
    f32x4 accla = {0.f, 0.f, 0.f, 0.f};
    f32x4 acclb = {0.f, 0.f, 0.f, 0.f};
    const f32x4 zero = {0.f, 0.f, 0.f, 0.f};
    const half8 ones = { (f16)1.f, (f16)1.f, (f16)1.f, (f16)1.f,
                         (f16)1.f, (f16)1.f, (f16)1.f, (f16)1.f };

    #pragma unroll 2
    for (int it = 0; it < 17; ++it) {
        half8 kf8 = *(const half8*)kptr;
        half8 vf  = *(const half8*)vptr;
        kptr += 512; vptr += 32;
        half4 kf0 = __builtin_shufflevector(kf8, kf8, 0, 1, 2, 3);
        half4 kf1 = __builtin_shufflevector(kf8, kf8, 4, 5, 6, 7);
        f32x4 s0a = __builtin_amdgcn_mfma_f32_16x16x16f16(kf0, qfa, zero, 0, 0, 0);
        f32x4 s1a = __builtin_amdgcn_mfma_f32_16x16x16f16(kf1, qfa, zero, 0, 0, 0);
        f32x4 s0b = __builtin_amdgcn_mfma_f32_16x16x16f16(kf0, qfb, zero, 0, 0, 0);
        f32x4 s1b = __builtin_amdgcn_mfma_f32_16x16x16f16(kf1, qfb, zero, 0, 0, 0);

        float a0 = EXP2(s0a[0]), a1 = EXP2(s0a[1]), a2 = EXP2(s0a[2]), a3 = EXP2(s0a[3]);
        float a4 = EXP2(s1a[0]), a5 = EXP2(s1a[1]), a6 = EXP2(s1a[2]), a7 = EXP2(s1a[3]);
        float b0 = EXP2(s0b[0]), b1 = EXP2(s0b[1]), b2 = EXP2(s0b[2]), b3 = EXP2(s0b[3]);
        float b4 = EXP2(s1b[0]), b5 = EXP2(s1b[1]), b6 = EXP2(s1b[2]), b7 = EXP2(s1b[3]);
        half8 pfa = pack8(a0, a1, a2, a3, a4, a5, a6, a7);
        half8 pfb = pack8(b0, b1, b2, b3, b4, b5, b6, b7);
        acca  = __builtin_amdgcn_mfma_f32_16x16x32_f16(pfa, vf,   acca,  0, 0, 0);
        accla = __builtin_amdgcn_mfma_f32_16x16x32_f16(pfa, ones, accla, 0, 0, 0);
        accb  = __builtin_amdgcn_mfma_f32_16x16x32_f16(pfb, vf,   accb,  0, 0, 0);
        acclb = __builtin_amdgcn_mfma_f32_16x16x32_f16(pfb, ones, acclb, 0, 0, 0);
    }

    if (col == 0) {                         // l row-sums live in every col of accl*
        #pragma unroll
        for (int r = 0; r < 4; r++) {
            sl[wave][0][quad * 4 + r] = accla[r];
            sl[wave][1][quad * 4 + r] = acclb[r];
        }
    }
    #pragma unroll
    for (int r = 0; r < 4; r++) {
        sacc[wave][0][(quad * 4 + r) * 16 + col] = acca[r];
        sacc[wave][1][(quad * 4 + r) * 16 + col] = accb[r];
    }
    __syncthreads();

    if (wave < 2) {                         // wave 0 -> q-tile 0, wave 1 -> q-tile 1
        int qt = wave;
        int b = bh >> 3, h = bh & 7;
        #pragma unroll
        for (int r = 0; r < 4; r++) {
            int ql = quad * 4 + r;
            float o = 0.f, lt = 0.f;
            #pragma unroll
            for (int w = 0; w < 16; w++) {
                o  += sacc[w][qt][ql * 16 + col];
                lt += sl[w][qt][ql];
            }
            hvw[((size_t)(b * N) + q0 + qt * 16 + ql) * DIM + h * DH + col] = (f16)(o / lt);
        }
    }
}

// ---------------------------------------------------------------------------
// Kernel 4: fused residual + LN2 + MFMA out-proj + residual.
// grid = 256 blocks (16 tokens, 4 of 8 col-tiles each; LN duplicated x2),
// 256 thr = 4 waves.
// ---------------------------------------------------------------------------
__global__ void __launch_bounds__(256) final_kernel(
    const f16* __restrict__ hvw, const float* __restrict__ x,
    const float* __restrict__ wout, const float* __restrict__ bout,
    const float* __restrict__ g2, const float* __restrict__ b2v,
    float* __restrict__ out)
{
    __shared__ f16 xn2[16][136];
    __shared__ float hres[16][132];
    int token0 = (blockIdx.x >> 1) * 16;
    int half = blockIdx.x & 1;
    int wave = threadIdx.x >> 6, lane = threadIdx.x & 63;

    #pragma unroll
    for (int tt = 0; tt < 4; tt++) {
        int tl = wave * 4 + tt;
        int token = token0 + tl;
        float h0 = (float)hvw[(size_t)token * DIM + lane]      + x[(size_t)token * DIM + lane];
        float h1 = (float)hvw[(size_t)token * DIM + lane + 64] + x[(size_t)token * DIM + lane + 64];
        float s = h0 + h1;
        for (int off = 32; off; off >>= 1) s += __shfl_xor(s, off, 64);
        float mu = s * (1.0f / DIM);
        float d0 = h0 - mu, d1 = h1 - mu;
        float vs = d0 * d0 + d1 * d1;
        for (int off = 32; off; off >>= 1) vs += __shfl_xor(vs, off, 64);
        float rs = rsqrtf(vs * (1.0f / DIM) + 1e-5f);
        xn2[tl][lane]      = (f16)(d0 * rs * g2[lane]      + b2v[lane]);
        xn2[tl][lane + 64] = (f16)(d1 * rs * g2[lane + 64] + b2v[lane + 64]);
        hres[tl][lane] = h0; hres[tl][lane + 64] = h1;
    }
    __syncthreads();

    int col = lane & 15, quad = lane >> 4;
    int ct = half * 4 + wave;               // this block's 4 col-tiles
    int cg = ct * 16 + col;
    const float* wrow = wout + (size_t)cg * DIM;
    f32x4 acc = {0.f, 0.f, 0.f, 0.f};
    #pragma unroll
    for (int kb = 0; kb < 4; kb++) {
        half8 a = *(const half8*)(&xn2[col][kb * 32 + quad * 8]);
        half8 w = cvt8(wrow + kb * 32 + quad * 8);
        acc = __builtin_amdgcn_mfma_f32_16x16x32_f16(a, w, acc, 0, 0, 0);
    }
    float bo = bout[cg];
    #pragma unroll
    for (int r = 0; r < 4; r++) {
        int tl = quad * 4 + r;
        out[(size_t)(token0 + tl) * DIM + cg] = acc[r] + bo + hres[tl][cg];
    }
}

// ===========================================================================
extern "C" void kernel_launch(void* const* d_in, const int* in_sizes, int n_in,
                              void* d_out, int out_size, void* d_ws, size_t ws_size,
                              hipStream_t stream)
{
    const float* x      = (const float*)d_in[0];
    const float* mem_kv = (const float*)d_in[1];
    const float* wq     = (const float*)d_in[2];
    const float* wkv    = (const float*)d_in[3];
    const float* wout   = (const float*)d_in[4];
    const float* bout   = (const float*)d_in[5];
    const float* g1     = (const float*)d_in[6];
    const float* b1     = (const float*)d_in[7];
    const float* g2     = (const float*)d_in[8];
    const float* b2     = (const float*)d_in[9];

    float* out = (float*)d_out;
    float* out_mem = out + (size_t)B * N * DIM;

    f16* krot = (f16*)((char*)d_ws + WS_KROT);
    f16* vt   = (f16*)((char*)d_ws + WS_VT);
    f16* qrot = (f16*)((char*)d_ws + WS_QROT);
    f16* hvw  = (f16*)((char*)d_ws + WS_HV);
    f16* xn16 = (f16*)((char*)d_ws + WS_XN);

    hipLaunchKernelGGL(prep_kernel, dim3(4608), dim3(256), 0, stream,
                       (const float4*)mem_kv, (float4*)out_mem, krot, vt,
                       x, g1, b1, xn16);
    hipLaunchKernelGGL(proj_kernel, dim3(768), dim3(256), 0, stream,
                       xn16, wq, wkv, out_mem, krot, vt, qrot);
    hipLaunchKernelGGL(attn_kernel, dim3(512), dim3(1024), 0, stream,
                       krot, vt, qrot, hvw);
    hipLaunchKernelGGL(final_kernel, dim3(256), dim3(256), 0, stream,
                       hvw, x, wout, bout, g2, b2, out);
}

// Round 4
// 138.180 us; speedup vs baseline: 1.1427x; 1.0250x over previous
//
#include <hip/hip_runtime.h>

#define B 4
#define N 512
#define M 8192
#define H 8
#define DH 16
#define DIM 128
#define J (M + N)          // 8704
#define LN10000_DIV8 1.1512925465f   // ln(10000)/8
#define LOG2E 1.44269504f

typedef _Float16 f16;
typedef _Float16 half4 __attribute__((ext_vector_type(4)));
typedef _Float16 half8 __attribute__((ext_vector_type(8)));
typedef __fp16 fp16x2 __attribute__((ext_vector_type(2)));
typedef float f32x4 __attribute__((ext_vector_type(4)));

#if __has_builtin(__builtin_amdgcn_exp2f)
#define EXP2(x) __builtin_amdgcn_exp2f(x)
#else
#define EXP2(x) exp2f(x)
#endif

union PK { fp16x2 v; unsigned int u; };

__device__ __forceinline__ half8 pack8(float a, float b, float c, float d,
                                       float e, float f, float g, float h) {
#if __has_builtin(__builtin_amdgcn_cvt_pkrtz)
    union { unsigned int u[4]; half8 h8; } r;
    PK p0, p1, p2, p3;
    p0.v = __builtin_amdgcn_cvt_pkrtz(a, b);
    p1.v = __builtin_amdgcn_cvt_pkrtz(c, d);
    p2.v = __builtin_amdgcn_cvt_pkrtz(e, f);
    p3.v = __builtin_amdgcn_cvt_pkrtz(g, h);
    r.u[0] = p0.u; r.u[1] = p1.u; r.u[2] = p2.u; r.u[3] = p3.u;
    return r.h8;
#else
    half8 r = { (f16)a, (f16)b, (f16)c, (f16)d, (f16)e, (f16)f, (f16)g, (f16)h };
    return r;
#endif
}

// ---- workspace layout ----
#define WS_KROT 0ull                              // f16 [32][J/32][512]  8,912,896 B (MFMA-frag tile order)
#define WS_VT   8912896ull                        // f16 [32][16][J]      8,912,896 B
#define WS_QROT 17825792ull                       // f16 [32][512][16]      524,288 B
#define WS_HV   18350080ull                       // f16 [2048][128]        524,288 B
#define WS_XN   18874368ull                       // f16 [2048][128]        524,288 B (dies after proj)

union V4  { f16 h[4];  uint2 u; };

__device__ __forceinline__ half8 cvt8(const float* p) {
    float4 a = *(const float4*)p, b = *(const float4*)(p + 4);
    half8 h = { (f16)a.x, (f16)a.y, (f16)a.z, (f16)a.w,
                (f16)b.x, (f16)b.y, (f16)b.z, (f16)b.w };
    return h;
}

// ---------------------------------------------------------------------------
// Kernel 1: LN1 -> xn16 (f16). 512 blocks x 256 thr (1 token/wave).
// Split out so the proj GEMM's only dependency finishes in ~2 us, letting
// prepKV (BW-bound) and proj (latency-bound) overlap in kernel 2.
// ---------------------------------------------------------------------------
__global__ void __launch_bounds__(256) ln_kernel(
    const float* __restrict__ x, const float* __restrict__ g1,
    const float* __restrict__ b1, f16* __restrict__ xn16)
{
    int wave = threadIdx.x >> 6, lane = threadIdx.x & 63;
    int token = blockIdx.x * 4 + wave;
    float v0 = x[(size_t)token * DIM + lane];
    float v1 = x[(size_t)token * DIM + lane + 64];
    float s = v0 + v1;
    for (int off = 32; off; off >>= 1) s += __shfl_xor(s, off, 64);
    float mu = s * (1.0f / DIM);
    float d0 = v0 - mu, d1 = v1 - mu;
    float vs = d0 * d0 + d1 * d1;
    for (int off = 32; off; off >>= 1) vs += __shfl_xor(vs, off, 64);
    float rs = rsqrtf(vs * (1.0f / DIM) + 1e-5f);
    xn16[(size_t)token * DIM + lane]      = (f16)(d0 * rs * g1[lane]      + b1[lane]);
    xn16[(size_t)token * DIM + lane + 64] = (f16)(d1 * rs * g1[lane + 64] + b1[lane + 64]);
}

// ---------------------------------------------------------------------------
// Kernel 2: merged {proj GEMM (blocks 0..767)} + {prepKV (blocks 768..4863)}.
// The two halves are independent (proj needs xn16 only; prepKV writes
// j<M krot/vt/copy, proj writes j>=M tails) and fill complementary pipes:
// prepKV is HBM-BW-bound, proj is MFMA/latency-bound -> cost ~ max, not sum.
//
// proj: [2048 tok x 128] @ [384 cols x 128]^T, one 16x16 tile per wave.
// ctile 0..7: Q head=ctile. ctile 8..23: kv-tile kt: head=kt>>1, V iff kt&1.
// Q output folds 0.25 * log2(e) so attn can use exp2.
// prepKV: copy old mem_kv (nontemporal store - never re-read) + emit
// repacked rotated-K + V^T.
// ---------------------------------------------------------------------------
__global__ void __launch_bounds__(256) prep_proj_kernel(
    const float4* __restrict__ src, float4* __restrict__ dstv,
    f16* __restrict__ krot, f16* __restrict__ vt,
    const f16* __restrict__ xn16, const float* __restrict__ wq,
    const float* __restrict__ wkv, f16* __restrict__ qrot)
{
    if (blockIdx.x < 768) {                 // ================= proj =================
        float* out_mem = (float*)dstv;
        int id = blockIdx.x * 4 + (threadIdx.x >> 6);
        int lane = threadIdx.x & 63;
        int ttile = id & 127, ctile = id >> 7;
        int token0 = ttile * 16;
        int col = lane & 15, quad = lane >> 4;

        const float* wbase = (ctile < 8) ? (wq + (size_t)(ctile * 16 + col) * DIM)
                                         : (wkv + (size_t)((ctile - 8) * 16 + col) * DIM);
        const f16* abase = xn16 + (size_t)(token0 + col) * DIM + quad * 8;

        f32x4 acc = {0.f, 0.f, 0.f, 0.f};
        #pragma unroll
        for (int kb = 0; kb < 4; kb++) {
            half8 a = *(const half8*)(abase + kb * 32);
            half8 w = cvt8(wbase + kb * 32 + quad * 8);
            acc = __builtin_amdgcn_mfma_f32_16x16x32_f16(a, w, acc, 0, 0, 0);
        }

        int e = col, r8 = e & 7;
        float f = __expf(-(float)r8 * LN10000_DIV8);
        int kt = ctile - 8;
        int head = (ctile < 8) ? ctile : (kt >> 1);
        int isV  = (ctile >= 8) ? (kt & 1) : 0;

        #pragma unroll
        for (int r = 0; r < 4; r++) {
            int tok = token0 + quad * 4 + r;
            int b = tok >> 9, i = tok & (N - 1);
            int bhh = b * H + head;
            float self = acc[r];
            float prt = __shfl_xor(self, 8, 64);  // partner dim e^8, same token

            if (ctile < 8) {                      // Q: rotary + scale (incl. log2e)
                float ang = (float)(M + i) * f;
                float sn, cs; __sincosf(ang, &sn, &cs);
                float rv = (self * cs + ((e < 8) ? -prt : prt) * sn) * (0.25f * LOG2E);
                qrot[((size_t)bhh * N + i) * 16 + e] = (f16)rv;
            } else if (!isV) {                    // K: fp32 append + repacked rotated fp16
                out_mem[((size_t)bhh * J + M + i) * 32 + e] = self;
                float ang = (float)(M + i) * f;
                float sn, cs; __sincosf(ang, &sn, &cs);
                float rv = self * cs + ((e < 8) ? -prt : prt) * sn;
                int jpos = M + i;
                int tilei = jpos >> 5, jj = jpos & 31;
                int col4 = (jj >> 3) * 4 + (jj & 3), frag = (jj >> 2) & 1;
                krot[(size_t)bhh * J * 16 + (size_t)tilei * 512 +
                     (e >> 2) * 128 + col4 * 8 + frag * 4 + (e & 3)] = (f16)rv;
            } else {                              // V: fp32 append + fp16 V^T
                out_mem[((size_t)bhh * J + M + i) * 32 + 16 + e] = self;
                vt[(size_t)bhh * 16 * J + (size_t)e * J + M + i] = (f16)self;
            }
        }
    } else {                                // ================ prepKV ================
        __shared__ float tile[64][33];
        int bid = blockIdx.x - 768;
        int bh = bid >> 7;
        int j0 = (bid & 127) * 64;
        int t = threadIdx.x;

        #pragma unroll
        for (int rep = 0; rep < 2; rep++) {
            int idx = t + rep * 256;
            int row = idx >> 3, c4 = idx & 7;
            float4 v = src[((size_t)bh * M + j0 + row) * 8 + c4];
            f32x4 vv = { v.x, v.y, v.z, v.w };
            __builtin_nontemporal_store(vv,
                (f32x4*)dstv + ((size_t)bh * J + j0 + row) * 8 + c4);
            tile[row][c4 * 4 + 0] = v.x; tile[row][c4 * 4 + 1] = v.y;
            tile[row][c4 * 4 + 2] = v.z; tile[row][c4 * 4 + 3] = v.w;
        }
        __syncthreads();

        if (t < 128) {                      // rotated K: 2 threads/row, 4 sincos each
            int row = t >> 1, rh = t & 1;
            int j = j0 + row;
            float lo4[4], hi4[4];
            #pragma unroll
            for (int i = 0; i < 4; i++) {
                int r = rh * 4 + i;
                float ang = (float)j * __expf(-(float)r * LN10000_DIV8);
                float sn, cs; __sincosf(ang, &sn, &cs);
                float lo = tile[row][r], hi = tile[row][r + 8];
                lo4[i] = lo * cs - hi * sn;
                hi4[i] = hi * cs + lo * sn;
            }
            int tilei = j >> 5, jj = j & 31;
            int col4 = (jj >> 3) * 4 + (jj & 3), frag = (jj >> 2) & 1;
            f16* base = krot + (size_t)bh * J * 16 + (size_t)tilei * 512 + col4 * 8 + frag * 4;
            V4 wl, wh;
            #pragma unroll
            for (int i = 0; i < 4; i++) { wl.h[i] = (f16)lo4[i]; wh.h[i] = (f16)hi4[i]; }
            *(uint2*)(base + rh * 128)       = wl.u;   // dims rh*4 .. rh*4+3
            *(uint2*)(base + (2 + rh) * 128) = wh.u;   // dims 8+rh*4 .. 8+rh*4+3
        }
        {                                   // V^T: dh-major, j contiguous
            int dh = t >> 4, c0 = (t & 15) * 4;
            V4 vv;
            #pragma unroll
            for (int i = 0; i < 4; i++) vv.h[i] = (f16)tile[c0 + i][16 + dh];
            *(uint2*)(vt + (size_t)bh * 16 * J + (size_t)dh * J + j0 + c0) = vv.u;
        }
    }
}

// ---------------------------------------------------------------------------
// Kernel 3: MFMA flash attention, no-max softmax via raw exp2.
// grid = 512 blocks (32 bh low-bits -> XCD-local L2 reuse, 16 qgroups of 32q)
// x 1024 threads = 16 waves -> 32 waves/CU (100% occupancy ceiling).
// Each wave: 2 q-tiles, J/16 = 544 keys (17 iters). Softmax denominator
// accumulated on the MFMA pipe via all-ones B operand. Output reduction
// spread over 512 threads (8 waves) instead of 128.
// ---------------------------------------------------------------------------
__global__ void __launch_bounds__(1024) attn_kernel(
    const f16* __restrict__ krot, const f16* __restrict__ vt,
    const f16* __restrict__ qrot, f16* __restrict__ hvw)
{
    __shared__ float sacc[16][2][256];
    __shared__ float sl[16][2][16];
    int bh = blockIdx.x & 31;               // same-bh blocks -> same XCD
    int q0 = (blockIdx.x >> 5) * 32;
    int wave = threadIdx.x >> 6, lane = threadIdx.x & 63;
    int col = lane & 15, quad = lane >> 4;

    const f16* vb = vt + (size_t)bh * 16 * J + (size_t)col * J;
    half4 qfa = *(const half4*)(qrot + ((size_t)bh * N + q0 + col) * 16 + quad * 4);
    half4 qfb = *(const half4*)(qrot + ((size_t)bh * N + q0 + 16 + col) * 16 + quad * 4);

    int jstart = wave * (J / 16);           // 544 = 17 iters of 32 keys
    const f16* kptr = krot + (size_t)bh * J * 16 + (size_t)jstart * 16 + lane * 8;
    const f16* vptr = vb + jstart + quad * 8;

    f32x4 acca = {0.f, 0.f, 0.f, 0.f};
    f32x4 accb = {0.f, 0.f, 0.f, 0.f};
    f32x4 accla = {0.f, 0.f, 0.f, 0.f};
    f32x4 acclb = {0.f, 0.f, 0.f, 0.f};
    const f32x4 zero = {0.f, 0.f, 0.f, 0.f};
    const half8 ones = { (f16)1.f, (f16)1.f, (f16)1.f, (f16)1.f,
                         (f16)1.f, (f16)1.f, (f16)1.f, (f16)1.f };

    #pragma unroll 2
    for (int it = 0; it < 17; ++it) {
        half8 kf8 = *(const half8*)kptr;
        half8 vf  = *(const half8*)vptr;
        kptr += 512; vptr += 32;
        half4 kf0 = __builtin_shufflevector(kf8, kf8, 0, 1, 2, 3);
        half4 kf1 = __builtin_shufflevector(kf8, kf8, 4, 5, 6, 7);
        f32x4 s0a = __builtin_amdgcn_mfma_f32_16x16x16f16(kf0, qfa, zero, 0, 0, 0);
        f32x4 s1a = __builtin_amdgcn_mfma_f32_16x16x16f16(kf1, qfa, zero, 0, 0, 0);
        f32x4 s0b = __builtin_amdgcn_mfma_f32_16x16x16f16(kf0, qfb, zero, 0, 0, 0);
        f32x4 s1b = __builtin_amdgcn_mfma_f32_16x16x16f16(kf1, qfb, zero, 0, 0, 0);

        float a0 = EXP2(s0a[0]), a1 = EXP2(s0a[1]), a2 = EXP2(s0a[2]), a3 = EXP2(s0a[3]);
        float a4 = EXP2(s1a[0]), a5 = EXP2(s1a[1]), a6 = EXP2(s1a[2]), a7 = EXP2(s1a[3]);
        float b0 = EXP2(s0b[0]), b1 = EXP2(s0b[1]), b2 = EXP2(s0b[2]), b3 = EXP2(s0b[3]);
        float b4 = EXP2(s1b[0]), b5 = EXP2(s1b[1]), b6 = EXP2(s1b[2]), b7 = EXP2(s1b[3]);
        half8 pfa = pack8(a0, a1, a2, a3, a4, a5, a6, a7);
        half8 pfb = pack8(b0, b1, b2, b3, b4, b5, b6, b7);
        acca  = __builtin_amdgcn_mfma_f32_16x16x32_f16(pfa, vf,   acca,  0, 0, 0);
        accla = __builtin_amdgcn_mfma_f32_16x16x32_f16(pfa, ones, accla, 0, 0, 0);
        accb  = __builtin_amdgcn_mfma_f32_16x16x32_f16(pfb, vf,   accb,  0, 0, 0);
        acclb = __builtin_amdgcn_mfma_f32_16x16x32_f16(pfb, ones, acclb, 0, 0, 0);
    }

    if (col == 0) {                         // l row-sums live in every col of accl*
        #pragma unroll
        for (int r = 0; r < 4; r++) {
            sl[wave][0][quad * 4 + r] = accla[r];
            sl[wave][1][quad * 4 + r] = acclb[r];
        }
    }
    #pragma unroll
    for (int r = 0; r < 4; r++) {
        sacc[wave][0][(quad * 4 + r) * 16 + col] = acca[r];
        sacc[wave][1][(quad * 4 + r) * 16 + col] = accb[r];
    }
    __syncthreads();

    if (threadIdx.x < 512) {                // 512 outputs -> 512 threads (8 waves)
        int t = threadIdx.x;
        int qt = t >> 8, ql = (t >> 4) & 15, c = t & 15;
        float o = 0.f, lt = 0.f;
        #pragma unroll
        for (int w = 0; w < 16; w++) {
            o  += sacc[w][qt][ql * 16 + c];
            lt += sl[w][qt][ql];
        }
        int b = bh >> 3, h = bh & 7;
        hvw[((size_t)(b * N) + q0 + qt * 16 + ql) * DIM + h * DH + c] = (f16)(o / lt);
    }
}

// ---------------------------------------------------------------------------
// Kernel 4: fused residual + LN2 + MFMA out-proj + residual.
// grid = 256 blocks (16 tokens, 4 of 8 col-tiles each; LN duplicated x2),
// 256 thr = 4 waves.
// ---------------------------------------------------------------------------
__global__ void __launch_bounds__(256) final_kernel(
    const f16* __restrict__ hvw, const float* __restrict__ x,
    const float* __restrict__ wout, const float* __restrict__ bout,
    const float* __restrict__ g2, const float* __restrict__ b2v,
    float* __restrict__ out)
{
    __shared__ f16 xn2[16][136];
    __shared__ float hres[16][132];
    int token0 = (blockIdx.x >> 1) * 16;
    int half = blockIdx.x & 1;
    int wave = threadIdx.x >> 6, lane = threadIdx.x & 63;

    #pragma unroll
    for (int tt = 0; tt < 4; tt++) {
        int tl = wave * 4 + tt;
        int token = token0 + tl;
        float h0 = (float)hvw[(size_t)token * DIM + lane]      + x[(size_t)token * DIM + lane];
        float h1 = (float)hvw[(size_t)token * DIM + lane + 64] + x[(size_t)token * DIM + lane + 64];
        float s = h0 + h1;
        for (int off = 32; off; off >>= 1) s += __shfl_xor(s, off, 64);
        float mu = s * (1.0f / DIM);
        float d0 = h0 - mu, d1 = h1 - mu;
        float vs = d0 * d0 + d1 * d1;
        for (int off = 32; off; off >>= 1) vs += __shfl_xor(vs, off, 64);
        float rs = rsqrtf(vs * (1.0f / DIM) + 1e-5f);
        xn2[tl][lane]      = (f16)(d0 * rs * g2[lane]      + b2v[lane]);
        xn2[tl][lane + 64] = (f16)(d1 * rs * g2[lane + 64] + b2v[lane + 64]);
        hres[tl][lane] = h0; hres[tl][lane + 64] = h1;
    }
    __syncthreads();

    int col = lane & 15, quad = lane >> 4;
    int ct = half * 4 + wave;               // this block's 4 col-tiles
    int cg = ct * 16 + col;
    const float* wrow = wout + (size_t)cg * DIM;
    f32x4 acc = {0.f, 0.f, 0.f, 0.f};
    #pragma unroll
    for (int kb = 0; kb < 4; kb++) {
        half8 a = *(const half8*)(&xn2[col][kb * 32 + quad * 8]);
        half8 w = cvt8(wrow + kb * 32 + quad * 8);
        acc = __builtin_amdgcn_mfma_f32_16x16x32_f16(a, w, acc, 0, 0, 0);
    }
    float bo = bout[cg];
    #pragma unroll
    for (int r = 0; r < 4; r++) {
        int tl = quad * 4 + r;
        out[(size_t)(token0 + tl) * DIM + cg] = acc[r] + bo + hres[tl][cg];
    }
}

// ===========================================================================
extern "C" void kernel_launch(void* const* d_in, const int* in_sizes, int n_in,
                              void* d_out, int out_size, void* d_ws, size_t ws_size,
                              hipStream_t stream)
{
    const float* x      = (const float*)d_in[0];
    const float* mem_kv = (const float*)d_in[1];
    const float* wq     = (const float*)d_in[2];
    const float* wkv    = (const float*)d_in[3];
    const float* wout   = (const float*)d_in[4];
    const float* bout   = (const float*)d_in[5];
    const float* g1     = (const float*)d_in[6];
    const float* b1     = (const float*)d_in[7];
    const float* g2     = (const float*)d_in[8];
    const float* b2     = (const float*)d_in[9];

    float* out = (float*)d_out;
    float* out_mem = out + (size_t)B * N * DIM;

    f16* krot = (f16*)((char*)d_ws + WS_KROT);
    f16* vt   = (f16*)((char*)d_ws + WS_VT);
    f16* qrot = (f16*)((char*)d_ws + WS_QROT);
    f16* hvw  = (f16*)((char*)d_ws + WS_HV);
    f16* xn16 = (f16*)((char*)d_ws + WS_XN);

    hipLaunchKernelGGL(ln_kernel, dim3(512), dim3(256), 0, stream,
                       x, g1, b1, xn16);
    hipLaunchKernelGGL(prep_proj_kernel, dim3(4864), dim3(256), 0, stream,
                       (const float4*)mem_kv, (float4*)out_mem, krot, vt,
                       xn16, wq, wkv, qrot);
    hipLaunchKernelGGL(attn_kernel, dim3(512), dim3(1024), 0, stream,
                       krot, vt, qrot, hvw);
    hipLaunchKernelGGL(final_kernel, dim3(256), dim3(256), 0, stream,
                       hvw, x, wout, bout, g2, b2, out);
}